// Round 7
// baseline (124.939 us; speedup 1.0000x reference)
//
#include <hip/hip_runtime.h>

#define N_PIX 4096
#define N_CH 256
#define KSEL 16
#define WCAP 64  // per-wave candidate cap (expected ~5-25 with block threshold)

__device__ __forceinline__ unsigned f2key(float f) {
  unsigned u = __float_as_uint(f);
  return u ^ ((unsigned)((int)u >> 31) | 0x80000000u);
}
__device__ __forceinline__ float key2f(unsigned k) {
  unsigned u = (k & 0x80000000u) ? (k ^ 0x80000000u) : ~k;
  return __uint_as_float(u);
}
__device__ __forceinline__ unsigned umax2(unsigned a, unsigned b) { return a > b ? a : b; }

// feat [B, C, N] -> feat_t [B, N, C], 32x32 LDS tile transpose
__global__ void transpose_feat_kernel(const float* __restrict__ feat,
                                      float* __restrict__ feat_t) {
  __shared__ float tile[32][33];
  const int b = blockIdx.z;
  const int n0 = blockIdx.x * 32;
  const int c0 = blockIdx.y * 32;
  const int tx = threadIdx.x, ty = threadIdx.y;
  const float* src = feat + (size_t)b * N_CH * N_PIX;
  float* dst = feat_t + (size_t)b * N_PIX * N_CH;
#pragma unroll
  for (int j = 0; j < 32; j += 8)
    tile[ty + j][tx] = src[(size_t)(c0 + ty + j) * N_PIX + n0 + tx];
  __syncthreads();
#pragma unroll
  for (int j = 0; j < 32; j += 8)
    dst[(size_t)(n0 + ty + j) * N_CH + c0 + tx] = tile[tx][ty + j];
}

// Block = 256 threads per row (16 keys/thread), 4 rows/block, prefetched.
// Selection by RANK (pipelined LDS broadcast all-pairs compares), not serial
// bit-radix:
//   stage 1: per-wave, rank each thread-max among the wave's 64 maxima
//            (16 x uint4 broadcast reads, ILP); T1_w = rank-15 value.
//            Block threshold T = max_w T1_w  (<= row's 16th-largest value:
//            within any wave, #thread-maxima > v16(row) <= #elems > v16
//            <= 15, so every T1_w <= v16; superset + >=16 candidates hold).
//   stage 2: ballot-rank compact elems >= T into per-wave LDS regions.
//   stage 3: every candidate's exact rank over all candidates (value desc,
//            index asc  == jax.lax.top_k tie semantics) via ~20-30 broadcast
//            reads; winners = rank < 16. No tie special-casing needed.
// 3 barriers/row, parity-buffered slabs. Single global pass, no spill.
template <bool FT>
__global__ __launch_bounds__(256) void topk_rank_kernel(
    const float* __restrict__ aff, const float* __restrict__ feat,
    float* __restrict__ out) {
  __shared__ __align__(16) unsigned s_max[4][64];  // wave-private maxima
  __shared__ unsigned s_t1[2][4];                  // per-wave 16th-largest max
  __shared__ unsigned s_wm[2][4];                  // per-wave max (softmax ref)
  __shared__ uint2 s_cand[2][4][WCAP];             // (key, idx)
  __shared__ unsigned s_cn[2][4];
  __shared__ uint2 s_wj[2][KSEL];                  // (exp(v-vmax) bits, idx)

  const int tid = threadIdx.x;
  const int lane = tid & 63;
  const int w = tid >> 6;
  // chunked bijective XCD swizzle: rg-consecutive blocks share an XCD so the
  // 4 blocks writing each 64B output line write-combine in one L2 (R6: 8.2MB).
  const int bid = blockIdx.x;
  const int rg = (bid & 7) * 256 + (bid >> 3);
  const int b = rg >> 10;
  const int i0 = (rg & 1023) * 4;
  const unsigned long long lt = (1ull << lane) - 1ull;

  const float* aff_rg = aff + (size_t)rg * 4 * N_PIX;
  float accs[4];

  // prefetch row 0
  float4 pv[4];
#pragma unroll
  for (int q = 0; q < 4; ++q) pv[q] = ((const float4*)aff_rg)[q * 256 + tid];

  for (int r = 0; r < 4; ++r) {
    const int p = r & 1;

    unsigned key[16];
#pragma unroll
    for (int q = 0; q < 4; ++q) {
      key[q * 4 + 0] = f2key(pv[q].x);
      key[q * 4 + 1] = f2key(pv[q].y);
      key[q * 4 + 2] = f2key(pv[q].z);
      key[q * 4 + 3] = f2key(pv[q].w);
    }
    // issue next row's loads; they fly under this row's compute
    if (r < 3) {
      const float4* nxt = (const float4*)(aff_rg + (size_t)(r + 1) * N_PIX);
#pragma unroll
      for (int q = 0; q < 4; ++q) pv[q] = nxt[q * 256 + tid];
    }

    // thread max over its 16 elements
    unsigned m = key[0];
#pragma unroll
    for (int e = 1; e < 16; ++e) m = umax2(m, key[e]);

    // ---- stage 1: rank m among the wave's 64 maxima (broadcast all-pairs) ----
    s_max[w][lane] = m;
    unsigned rank1 = 0, wmax = 0;
#pragma unroll
    for (int j4 = 0; j4 < 16; ++j4) {
      const uint4 mm = *(const uint4*)&s_max[w][j4 * 4];  // broadcast b128
      rank1 += (mm.x > m) || (mm.x == m && (j4 * 4 + 0) < lane);
      rank1 += (mm.y > m) || (mm.y == m && (j4 * 4 + 1) < lane);
      rank1 += (mm.z > m) || (mm.z == m && (j4 * 4 + 2) < lane);
      rank1 += (mm.w > m) || (mm.w == m && (j4 * 4 + 3) < lane);
      wmax = umax2(wmax, umax2(umax2(mm.x, mm.y), umax2(mm.z, mm.w)));
    }
    if (rank1 == 15) s_t1[p][w] = m;   // exactly one lane per wave
    if (lane == 0) s_wm[p][w] = wmax;
    __syncthreads();  // B0

    const unsigned T = umax2(umax2(s_t1[p][0], s_t1[p][1]),
                             umax2(s_t1[p][2], s_t1[p][3]));
    const float vmax = key2f(umax2(umax2(s_wm[p][0], s_wm[p][1]),
                                   umax2(s_wm[p][2], s_wm[p][3])));

    // ---- stage 2: compact elements >= T into per-wave region (ballot-rank) ----
    unsigned base = 0;
#pragma unroll
    for (int e = 0; e < 16; ++e) {
      const bool sel = key[e] >= T;
      const unsigned long long mk = __ballot(sel);
      if (sel) {
        const unsigned pos = base + (unsigned)__popcll(mk & lt);
        if (pos < WCAP)
          s_cand[p][w][pos] =
              make_uint2(key[e], (unsigned)((e >> 2) * 1024 + tid * 4 + (e & 3)));
      }
      base += (unsigned)__popcll(mk);
    }
    if (__builtin_expect(base > WCAP, 0)) {
      // parachute (measure-zero): exact serial radix for this wave's quarter;
      // its exact 16th value T2 >= T, and wave's share of the row top-16 is
      // within its own top-16, all >= T2.
      unsigned p2 = 0, need2 = KSEL;
      for (int bit = 31; bit >= 0; --bit) {
        const unsigned want = (p2 << 1) | 1u;
        unsigned cnt = 0;
#pragma unroll
        for (int e = 0; e < 16; ++e)
          cnt += (unsigned)__popcll(__ballot((key[e] >> bit) == want));
        const bool take = cnt >= need2;
        p2 = want - (take ? 0u : 1u);
        need2 = take ? need2 : need2 - cnt;
      }
      base = 0;
#pragma unroll
      for (int e = 0; e < 16; ++e) {
        const bool sel = key[e] >= p2;
        const unsigned long long mk = __ballot(sel);
        if (sel) {
          const unsigned pos = base + (unsigned)__popcll(mk & lt);
          if (pos < WCAP)
            s_cand[p][w][pos] =
                make_uint2(key[e], (unsigned)((e >> 2) * 1024 + tid * 4 + (e & 3)));
        }
        base += (unsigned)__popcll(mk);
      }
    }
    if (lane == 0) s_cn[p][w] = base < WCAP ? base : WCAP;
    __syncthreads();  // B1

    // ---- stage 3: exact rank of every candidate over all candidates ----
    // thread (w, lane) owns candidate slot lane of its own wave's region
    const unsigned nown = s_cn[p][w];
    unsigned cv = 0, cj = 0;
    const bool valid = (unsigned)lane < nown;
    if (valid) {
      const uint2 t = s_cand[p][w][lane];
      cv = t.x; cj = t.y;
    }
    unsigned rank = 0;
#pragma unroll
    for (int u = 0; u < 4; ++u) {
      const unsigned nu = s_cn[p][u];  // wave-uniform trip count
      for (unsigned j2 = 0; j2 < nu; ++j2) {
        const uint2 t = s_cand[p][u][j2];  // broadcast read
        rank += (t.x > cv) || (t.x == cv && t.y < cj);
      }
    }
    if (valid && rank < KSEL)
      s_wj[p][rank] = make_uint2(__float_as_uint(__expf(key2f(cv) - vmax)), cj);
    __syncthreads();  // B2

    // ---- gather: thread = channel; deferred softmax normalization ----
    float ssum = 0.f, a = 0.f;
    if (FT) {
      const float* fb = feat + (size_t)b * N_PIX * N_CH + tid;  // [B,N,C]
#pragma unroll
      for (int k2 = 0; k2 < KSEL; ++k2) {
        const uint2 t = s_wj[p][k2];
        const float ew = __uint_as_float(t.x);
        ssum += ew;
        a = fmaf(ew, fb[(size_t)t.y * N_CH], a);
      }
    } else {
      const float* fb = feat + ((size_t)(b * N_CH + tid)) * N_PIX;  // [B,C,N]
#pragma unroll
      for (int k2 = 0; k2 < KSEL; ++k2) {
        const uint2 t = s_wj[p][k2];
        const float ew = __uint_as_float(t.x);
        ssum += ew;
        a = fmaf(ew, fb[t.y], a);
      }
    }
    accs[r] = a / ssum;
    // next row uses the other parity slabs; no trailing barrier
  }

  // out[b, c, i0..i0+3] as one float4 per channel (full-line write-combining)
  float4 o;
  o.x = accs[0]; o.y = accs[1]; o.z = accs[2]; o.w = accs[3];
  *(float4*)(out + ((size_t)(b * N_CH + tid)) * N_PIX + i0) = o;
}

extern "C" void kernel_launch(void* const* d_in, const int* in_sizes, int n_in,
                              void* d_out, int out_size, void* d_ws, size_t ws_size,
                              hipStream_t stream) {
  const float* aff = (const float*)d_in[0];
  const float* feat = (const float*)d_in[1];
  float* out = (float*)d_out;
  const size_t feat_t_bytes = (size_t)2 * N_PIX * N_CH * sizeof(float);
  if (ws_size >= feat_t_bytes) {
    float* feat_t = (float*)d_ws;
    dim3 tb(32, 8, 1);
    dim3 tg(N_PIX / 32, N_CH / 32, 2);
    transpose_feat_kernel<<<tg, tb, 0, stream>>>(feat, feat_t);
    topk_rank_kernel<true><<<2048, 256, 0, stream>>>(aff, feat_t, out);
  } else {
    topk_rank_kernel<false><<<2048, 256, 0, stream>>>(aff, feat, out);
  }
}